// Round 8
// baseline (183.348 us; speedup 1.0000x reference)
//
#include <hip/hip_runtime.h>

typedef __attribute__((ext_vector_type(8))) short bf16x8;
typedef __attribute__((ext_vector_type(4))) float f32x4;
typedef __attribute__((ext_vector_type(16))) float f32x16;

#define B_  2
#define S_  2048
#define DM  512
#define KD  256
#define HD  32
#define NH  8

__device__ __forceinline__ float bf2f(ushort u) {
    return __uint_as_float(((uint)u) << 16);
}
__device__ __forceinline__ ushort f2bf(float f) {
    uint x = __float_as_uint(f);
    return (ushort)((x + 0x7fffu + ((x >> 16) & 1u)) >> 16);  // RNE
}
// gfx950 packed f32->bf16 (RNE), 1 instr per 2 elements
__device__ __forceinline__ uint cvt_pk_bf16(float lo, float hi) {
    uint r;
    asm("v_cvt_pk_bf16_f32 %0, %1, %2" : "=v"(r) : "v"(lo), "v"(hi));
    return r;
}
#define MFMA __builtin_amdgcn_mfma_f32_16x16x32_bf16
#define MFMA32 __builtin_amdgcn_mfma_f32_32x32x16_bf16

__device__ __forceinline__ int detect_isbf(const ushort* __restrict__ q)
{
    int lane = threadIdx.x & 63;
    int e = (q[lane] >> 7) & 0xFF;
    unsigned long long m = __ballot(e >= 100 && e <= 133);
    return __popcll(m) >= 58;
}

// ---- W transposes + biases; output in PACKED fragment layout [n/16][k/8][16][8]
__global__ __launch_bounds__(256) void transpose_w(
    const void* __restrict__ Wq, const void* __restrict__ Wk, const void* __restrict__ Wv,
    const void* __restrict__ Wo,
    const void* __restrict__ bq, const void* __restrict__ bk,
    const void* __restrict__ bv, const void* __restrict__ bo,
    const ushort* __restrict__ qsrc,
    ushort* __restrict__ Wt, ushort* __restrict__ Wot, float* __restrict__ biasf)
{
    int isbf = detect_isbf(qsrc);
    int bid = blockIdx.x;
    if (bid >= 512) {
        for (int i = threadIdx.x; i < 1280; i += 256) {
            const void* bp; int off;
            if (i < 256)      { bp = bq; off = i; }
            else if (i < 512) { bp = bk; off = i - 256; }
            else if (i < 768) { bp = bv; off = i - 512; }
            else              { bp = bo; off = i - 768; }
            biasf[i] = isbf ? bf2f(((const ushort*)bp)[off]) : ((const float*)bp)[off];
        }
        return;
    }
    const void* W; int R, C; ushort* T;
    int m = bid >> 7, tix = bid & 127;
    if (m < 3) { W = (m == 0) ? Wq : (m == 1) ? Wk : Wv; R = 512; C = 256; T = Wt + m * 131072; }
    else       { W = Wo; R = 256; C = 512; T = Wot; }
    int tilesPerRow = C >> 5;
    int r0 = (tix / tilesPerRow) * 32, c0 = (tix % tilesPerRow) * 32;
    __shared__ float lds[32][33];
    int t = threadIdx.x;
    int rr = t >> 3, cc = (t & 7) * 4;
    if (isbf) {
        const ushort* Ws = (const ushort*)W;
        #pragma unroll
        for (int j = 0; j < 4; ++j) lds[rr][cc + j] = bf2f(Ws[(size_t)(r0 + rr) * C + c0 + cc + j]);
    } else {
        float4 v = *(const float4*)((const float*)W + (size_t)(r0 + rr) * C + c0 + cc);
        lds[rr][cc + 0] = v.x; lds[rr][cc + 1] = v.y; lds[rr][cc + 2] = v.z; lds[rr][cc + 3] = v.w;
    }
    __syncthreads();
    ushort4 o;
    o.x = f2bf(lds[cc + 0][rr]); o.y = f2bf(lds[cc + 1][rr]);
    o.z = f2bf(lds[cc + 2][rr]); o.w = f2bf(lds[cc + 3][rr]);
    int n = c0 + rr, k = r0 + cc;
    *(ushort4*)(T + ((((size_t)(n >> 4) * (R >> 3) + (k >> 3)) * 16 + (n & 15)) << 3) + (k & 7)) = o;
}

// ---- QKV GEMM (R6 structure, unchanged): 16-row m-tiles, packed-B, cvt_pk
__global__ __launch_bounds__(256) void qkv_gemm(
    const void* __restrict__ Q, const void* __restrict__ K, const void* __restrict__ V,
    const ushort* __restrict__ Wt, const float* __restrict__ biasf,
    ushort* __restrict__ qh, ushort* __restrict__ kh, ushort* __restrict__ vT)
{
    int isbf = detect_isbf((const ushort*)Q);
    int y = blockIdx.y;
    const void* X = (y == 0) ? Q : (y == 1) ? K : V;
    int wave = threadIdx.x >> 6, lane = threadIdx.x & 63;
    int l16 = lane & 15, quad = lane >> 4;
    int m0 = blockIdx.x * 16;           // grid.x = 256
    int n0 = wave * 64;
    const ushort* W = Wt + (size_t)y * (256 * 512);

    auto loadA = [&](int ks, bf16x8* a) {
        if (isbf) {
            *a = *(const bf16x8*)((const ushort*)X + (size_t)(m0 + l16) * 512 + ks + quad * 8);
        } else {
            const float* p = (const float*)X + (size_t)(m0 + l16) * 512 + ks + quad * 8;
            float4 f0 = *(const float4*)p, f1 = *(const float4*)(p + 4);
            union { uint u[4]; bf16x8 v; } cv;
            cv.u[0] = cvt_pk_bf16(f0.x, f0.y);
            cv.u[1] = cvt_pk_bf16(f0.z, f0.w);
            cv.u[2] = cvt_pk_bf16(f1.x, f1.y);
            cv.u[3] = cvt_pk_bf16(f1.z, f1.w);
            *a = cv.v;
        }
    };
    auto loadB = [&](int ks, bf16x8* b) {
        #pragma unroll
        for (int j = 0; j < 4; ++j)
            b[j] = *(const bf16x8*)(W + (((size_t)((n0 >> 4) + j) * 64 + (ks >> 3) + quad) * 16 + l16) * 8);
    };

    f32x4 acc[4] = {};
    bf16x8 aC, bC[4], aN, bN[4];
    loadA(0, &aC); loadB(0, bC);
    for (int ks = 0; ks < 512; ks += 32) {
        if (ks + 32 < 512) { loadA(ks + 32, &aN); loadB(ks + 32, bN); }
        #pragma unroll
        for (int j = 0; j < 4; ++j)
            acc[j] = MFMA(aC, bC[j], acc[j], 0, 0, 0);
        aC = aN;
        #pragma unroll
        for (int j = 0; j < 4; ++j) bC[j] = bN[j];
    }
    if (y < 2) {
        ushort* out = (y == 0) ? qh : kh;
        #pragma unroll
        for (int j = 0; j < 4; ++j) {
            int n = n0 + 16 * j + l16;
            float bs = biasf[y * 256 + n];
            int h = n >> 5, d = n & 31;
            #pragma unroll
            for (int r = 0; r < 4; ++r) {
                int rg = m0 + quad * 4 + r;
                int bb = rg >> 11, ss = rg & 2047;
                out[((((size_t)bb * NH + h) * S_ + ss) << 5) + d] = f2bf(acc[j][r] + bs);
            }
        }
    } else {
        int rg0 = m0 + quad * 4;
        int bb = rg0 >> 11, s0 = rg0 & 2047;
        #pragma unroll
        for (int j = 0; j < 4; ++j) {
            int n = n0 + 16 * j + l16;
            float bs = biasf[2 * 256 + n];
            int h = n >> 5, d = n & 31;
            ushort4 o;
            o.x = f2bf(acc[j][0] + bs); o.y = f2bf(acc[j][1] + bs);
            o.z = f2bf(acc[j][2] + bs); o.w = f2bf(acc[j][3] + bs);
            *(ushort4*)(vT + (((size_t)(bb * NH + h) * HD + d) * S_) + s0) = o;
        }
    }
}

// ---- attention. R11 = R10 with the permlane32_swap DIRECTION fixed.
// v_permlane32_swap_b32 DST,SRC swaps DST.row1 <-> SRC.row0. With u=pk(p[2i],
// p[2i+1]) (lane-local low k'-group) and w=pk(p[2i+4],p[2i+5]) (high group),
// DST=u,SRC=w yields u'={u.row0,w.row0}=frag word(2i) and w'={u.row1,w.row1}=
// frag word(2i+2) — one swap fills two words (T12). R10 had DST/SRC reversed,
// permuting P against V (absmax 4e-2).
__global__ __launch_bounds__(256) void attn(
    const ushort* __restrict__ qh, const ushort* __restrict__ kh,
    const ushort* __restrict__ vT, const void* __restrict__ maskp,
    float* __restrict__ pO, float* __restrict__ pl)
{
    __shared__ float ldsM[4][2][32][33];   // 33.8 KB, per-wave double buffer
    int isbf;
    {
        int lane = threadIdx.x & 63;
        ushort u = ((const ushort*)maskp)[lane];
        int e = (u >> 7) & 0xFF;
        unsigned long long m = __ballot(e >= 100 && e <= 133);
        isbf = __popcll(m) >= 58;
    }
    int wave = threadIdx.x >> 6, lane = threadIdx.x & 63;
    int l31 = lane & 31, hi = lane >> 5;
    int wid = blockIdx.x * 4 + wave;        // 2048 waves
    int chunk = wid & 1, qt32 = (wid >> 1) & 63, bh = wid >> 7;
    int b = bh >> 3;
    int q0 = qt32 * 32;
    const ushort* qb = qh + (size_t)bh * S_ * HD;
    const ushort* kb = kh + (size_t)bh * S_ * HD;
    const ushort* vb = vT + (size_t)bh * HD * S_;
    const ushort* mbb = (const ushort*)maskp + (size_t)b * S_ * S_;
    const float*  mbf = (const float*)maskp  + (size_t)b * S_ * S_;

    // Q B-frags, hoisted for the whole kernel:
    // B[d=hi*8+j][q=l31] = Q[q0+l31][d]  (two d-halves)
    bf16x8 bq0 = *(const bf16x8*)(qb + (size_t)(q0 + l31) * HD + hi * 8);
    bf16x8 bq1 = *(const bf16x8*)(qb + (size_t)(q0 + l31) * HD + 16 + hi * 8);

    f32x16 O = {0,0,0,0,0,0,0,0,0,0,0,0,0,0,0,0};
    const f32x16 Z = {0,0,0,0,0,0,0,0,0,0,0,0,0,0,0,0};
    float lsum = 0.0f;

    int srow = (lane >> 3) & 7, scol = (lane & 7) * 4;   // staging: 8 rows x 8 float4
    float4 g[4];                                          // in-flight mask tile

    auto loadMg = [&](int k0) {
        if (isbf) {
            #pragma unroll
            for (int i = 0; i < 4; ++i) {
                ushort4 u = *(const ushort4*)(mbb + (size_t)(q0 + i * 8 + srow) * S_ + k0 + scol);
                float4 f; f.x = bf2f(u.x); f.y = bf2f(u.y); f.z = bf2f(u.z); f.w = bf2f(u.w);
                g[i] = f;
            }
        } else {
            #pragma unroll
            for (int i = 0; i < 4; ++i)
                g[i] = *(const float4*)(mbf + (size_t)(q0 + i * 8 + srow) * S_ + k0 + scol);
        }
    };
    auto writeM = [&](int buf) {
        #pragma unroll
        for (int i = 0; i < 4; ++i) {
            ldsM[wave][buf][i * 8 + srow][scol + 0] = g[i].x;
            ldsM[wave][buf][i * 8 + srow][scol + 1] = g[i].y;
            ldsM[wave][buf][i * 8 + srow][scol + 2] = g[i].z;
            ldsM[wave][buf][i * 8 + srow][scol + 3] = g[i].w;
        }
    };
    auto loadK = [&](int k0, bf16x8* K2) {
        K2[0] = *(const bf16x8*)(kb + (size_t)(k0 + l31) * HD + hi * 8);
        K2[1] = *(const bf16x8*)(kb + (size_t)(k0 + l31) * HD + 16 + hi * 8);
    };
    auto loadV = [&](int k0, bf16x8* V2) {
        V2[0] = *(const bf16x8*)(vb + (size_t)l31 * S_ + k0 + hi * 8);
        V2[1] = *(const bf16x8*)(vb + (size_t)l31 * S_ + k0 + 16 + hi * 8);
    };

    int kbase = chunk * 1024;

    auto sub = [&](int buf, bf16x8* Kc, bf16x8* Vc, bf16x8* Kn, bf16x8* Vn, int t) {
        // 1. mask regs for tile t (acc layout: row q=l31, col k'=(r&3)+8*(r>>2)+4*hi)
        float Mreg[16];
        #pragma unroll
        for (int r = 0; r < 16; ++r)
            Mreg[r] = ldsM[wave][buf][l31][(r & 3) + ((r >> 2) << 3) + (hi << 2)];
        // 2. prefetch K/V for t+1 (clamped at range end; redundant load, unread)
        int ktn = kbase + ((t + 1 < 32) ? (t + 1) : 31) * 32;
        loadK(ktn, Kn); loadV(ktn, Vn);
        // 3. QK^T swapped: S^T[k'][q]
        f32x16 S = MFMA32(Kc[0], bq0, Z, 0, 0, 0);
        S = MFMA32(Kc[1], bq1, S, 0, 0, 0);
        // 4. write mask tile t+1 (globals issued one substep ago) & issue t+2
        writeM(buf ^ 1);
        int ktn2 = kbase + ((t + 2 < 32) ? (t + 2) : 31) * 32;
        loadMg(ktn2);
        // 5. softmax in registers
        float p[16];
        #pragma unroll
        for (int r = 0; r < 16; ++r) {
            p[r] = __expf(fmaf(S[r], 0.0625f, Mreg[r]));
            lsum += p[r];
        }
        // 6. P -> bf16 A-frags via cvt_pk + permlane32_swap (DST=low-group!)
        union { uint u[4]; bf16x8 v; } pa0, pa1;
        {
            uint u0 = cvt_pk_bf16(p[0], p[1]),  w0 = cvt_pk_bf16(p[4], p[5]);
            uint u1 = cvt_pk_bf16(p[2], p[3]),  w1 = cvt_pk_bf16(p[6], p[7]);
            asm volatile("v_permlane32_swap_b32 %0, %1" : "+v"(u0), "+v"(w0));
            asm volatile("v_permlane32_swap_b32 %0, %1" : "+v"(u1), "+v"(w1));
            pa0.u[0] = u0; pa0.u[1] = u1; pa0.u[2] = w0; pa0.u[3] = w1;
            uint u2 = cvt_pk_bf16(p[8], p[9]),   w2 = cvt_pk_bf16(p[12], p[13]);
            uint u3 = cvt_pk_bf16(p[10], p[11]), w3 = cvt_pk_bf16(p[14], p[15]);
            asm volatile("v_permlane32_swap_b32 %0, %1" : "+v"(u2), "+v"(w2));
            asm volatile("v_permlane32_swap_b32 %0, %1" : "+v"(u3), "+v"(w3));
            pa1.u[0] = u2; pa1.u[1] = u3; pa1.u[2] = w2; pa1.u[3] = w3;
        }
        // 7. PV: O[q][d'] += P·V
        O = MFMA32(pa0.v, Vc[0], O, 0, 0, 0);
        O = MFMA32(pa1.v, Vc[1], O, 0, 0, 0);
    };

    bf16x8 KA[2], VA[2], KB[2], VB[2];
    loadK(kbase, KA); loadV(kbase, VA);
    loadMg(kbase); writeM(0);
    loadMg(kbase + 32);
    for (int t = 0; t < 32; t += 2) {
        sub(0, KA, VA, KB, VB, t);
        sub(1, KB, VB, KA, VA, t + 1);
    }

    // epilogue: row sums (combine hi halves) + pO/pl in the R6 layout
    float tot = lsum + __shfl_xor(lsum, 32, 64);
    int wid16_0 = ((bh * 128) + qt32 * 2 + 0) * 2 + chunk;
    int wid16_1 = ((bh * 128) + qt32 * 2 + 1) * 2 + chunk;
    if (lane < 32) {
        int q = l31;
        int w16 = (q < 16) ? wid16_0 : wid16_1;
        pl[w16 * 16 + (q & 15)] = tot;
    }
    #pragma unroll
    for (int r = 0; r < 16; ++r) {
        int q = (r & 3) + ((r >> 2) << 3) + (hi << 2);
        int w16 = (q < 16) ? wid16_0 : wid16_1;
        pO[(size_t)w16 * 512 + (q & 15) * 32 + l31] = O[r];
    }
}

// ---- out projection (R6 structure, unchanged): 16-row m-tiles, packed-B, cvt_pk
__global__ __launch_bounds__(256) void out_proj(
    const float* __restrict__ pO, const float* __restrict__ pl,
    const ushort* __restrict__ Wot, const float* __restrict__ biasf,
    float* __restrict__ out)
{
    int wave = threadIdx.x >> 6, lane = threadIdx.x & 63;
    int l16 = lane & 15, quad = lane >> 4;
    int m0 = (blockIdx.x >> 1) * 16;                  // grid = 512
    int n0 = (blockIdx.x & 1) * 256 + wave * 64;
    f32x4 acc[4] = {};
    for (int ks = 0; ks < 256; ks += 32) {
        int h = ks >> 5;
        bf16x8 a, b[4];
        {
            int row = m0 + l16;
            int bb = row >> 11, s = row & 2047;
            int qt = s >> 4, r16 = s & 15;
            int wid0 = ((bb * NH + h) << 8) | (qt << 1);
            const float* p0 = pO + (size_t)wid0 * 512 + r16 * 32 + quad * 8;
            float4 x0 = *(const float4*)p0,         x1 = *(const float4*)(p0 + 4);
            float4 y0 = *(const float4*)(p0 + 512), y1 = *(const float4*)(p0 + 516);
            float il = 1.0f / (pl[wid0 * 16 + r16] + pl[(wid0 + 1) * 16 + r16]);
            union { uint u[4]; bf16x8 v; } cv;
            cv.u[0] = cvt_pk_bf16((x0.x + y0.x) * il, (x0.y + y0.y) * il);
            cv.u[1] = cvt_pk_bf16((x0.z + y0.z) * il, (x0.w + y0.w) * il);
            cv.u[2] = cvt_pk_bf16((x1.x + y1.x) * il, (x1.y + y1.y) * il);
            cv.u[3] = cvt_pk_bf16((x1.z + y1.z) * il, (x1.w + y1.w) * il);
            a = cv.v;
        }
        #pragma unroll
        for (int j = 0; j < 4; ++j)
            b[j] = *(const bf16x8*)(Wot + (((size_t)((n0 >> 4) + j) * 32 + (ks >> 3) + quad) * 16 + l16) * 8);
        #pragma unroll
        for (int j = 0; j < 4; ++j)
            acc[j] = MFMA(a, b[j], acc[j], 0, 0, 0);
    }
    #pragma unroll
    for (int j = 0; j < 4; ++j) {
        int n = n0 + 16 * j + l16;
        float bs = biasf[768 + n];
        #pragma unroll
        for (int r = 0; r < 4; ++r) {
            int rg = m0 + quad * 4 + r;
            out[(size_t)rg * DM + n] = acc[j][r] + bs;
        }
    }
}

extern "C" void kernel_launch(void* const* d_in, const int* in_sizes, int n_in,
                              void* d_out, int out_size, void* d_ws, size_t ws_size,
                              hipStream_t stream)
{
    const void* V    = d_in[0];
    const void* Q    = d_in[1];
    const void* K    = d_in[2];
    const void* mask = d_in[3];
    const void* Wq = d_in[4];  const void* bq = d_in[5];
    const void* Wk = d_in[6];  const void* bk = d_in[7];
    const void* Wv = d_in[8];  const void* bv = d_in[9];
    const void* Wo = d_in[10]; const void* bo = d_in[11];
    float* out = (float*)d_out;

    char* ws = (char*)d_ws;
    float*  biasf = (float*)ws;                    // 1280 fp32
    ushort* Wt  = (ushort*)(ws + 8192);            // 393,216 ushorts
    ushort* Wot = Wt  + 393216;                    // 131,072
    ushort* qh  = Wot + 131072;                    // 1,048,576 each (2 MB)
    ushort* kh  = qh  + 1048576;
    ushort* vT  = kh  + 1048576;
    float*  pO  = (float*)(vT + 1048576);          // 4096 x 512 fp32 (8.4 MB)
    float*  pl  = pO + 4096 * 512;                 // 65,536 fp32

    transpose_w<<<513, 256, 0, stream>>>(Wq, Wk, Wv, Wo, bq, bk, bv, bo,
                                         (const ushort*)Q, Wt, Wot, biasf);
    qkv_gemm<<<dim3(256, 3), 256, 0, stream>>>(Q, K, V, Wt, biasf, qh, kh, vT);
    attn<<<512, 256, 0, stream>>>(qh, kh, vT, mask, pO, pl);
    out_proj<<<512, 256, 0, stream>>>(pO, pl, Wot, biasf, out);
}

// Round 9
// 177.329 us; speedup vs baseline: 1.0339x; 1.0339x over previous
//
#include <hip/hip_runtime.h>

typedef __attribute__((ext_vector_type(8))) short bf16x8;
typedef __attribute__((ext_vector_type(4))) float f32x4;
typedef __attribute__((ext_vector_type(16))) float f32x16;

#define B_  2
#define S_  2048
#define DM  512
#define KD  256
#define HD  32
#define NH  8

__device__ __forceinline__ float bf2f(ushort u) {
    return __uint_as_float(((uint)u) << 16);
}
__device__ __forceinline__ ushort f2bf(float f) {
    uint x = __float_as_uint(f);
    return (ushort)((x + 0x7fffu + ((x >> 16) & 1u)) >> 16);  // RNE
}
// gfx950 packed f32->bf16 (RNE), 1 instr per 2 elements
__device__ __forceinline__ uint cvt_pk_bf16(float lo, float hi) {
    uint r;
    asm("v_cvt_pk_bf16_f32 %0, %1, %2" : "=v"(r) : "v"(lo), "v"(hi));
    return r;
}
#define MFMA __builtin_amdgcn_mfma_f32_16x16x32_bf16
#define MFMA32 __builtin_amdgcn_mfma_f32_32x32x16_bf16

__device__ __forceinline__ int detect_isbf(const ushort* __restrict__ q)
{
    int lane = threadIdx.x & 63;
    int e = (q[lane] >> 7) & 0xFF;
    unsigned long long m = __ballot(e >= 100 && e <= 133);
    return __popcll(m) >= 58;
}

// ---- W transposes + biases; output in PACKED fragment layout [n/16][k/8][16][8]
__global__ __launch_bounds__(256) void transpose_w(
    const void* __restrict__ Wq, const void* __restrict__ Wk, const void* __restrict__ Wv,
    const void* __restrict__ Wo,
    const void* __restrict__ bq, const void* __restrict__ bk,
    const void* __restrict__ bv, const void* __restrict__ bo,
    const ushort* __restrict__ qsrc,
    ushort* __restrict__ Wt, ushort* __restrict__ Wot, float* __restrict__ biasf)
{
    int isbf = detect_isbf(qsrc);
    int bid = blockIdx.x;
    if (bid >= 512) {
        for (int i = threadIdx.x; i < 1280; i += 256) {
            const void* bp; int off;
            if (i < 256)      { bp = bq; off = i; }
            else if (i < 512) { bp = bk; off = i - 256; }
            else if (i < 768) { bp = bv; off = i - 512; }
            else              { bp = bo; off = i - 768; }
            biasf[i] = isbf ? bf2f(((const ushort*)bp)[off]) : ((const float*)bp)[off];
        }
        return;
    }
    const void* W; int R, C; ushort* T;
    int m = bid >> 7, tix = bid & 127;
    if (m < 3) { W = (m == 0) ? Wq : (m == 1) ? Wk : Wv; R = 512; C = 256; T = Wt + m * 131072; }
    else       { W = Wo; R = 256; C = 512; T = Wot; }
    int tilesPerRow = C >> 5;
    int r0 = (tix / tilesPerRow) * 32, c0 = (tix % tilesPerRow) * 32;
    __shared__ float lds[32][33];
    int t = threadIdx.x;
    int rr = t >> 3, cc = (t & 7) * 4;
    if (isbf) {
        const ushort* Ws = (const ushort*)W;
        #pragma unroll
        for (int j = 0; j < 4; ++j) lds[rr][cc + j] = bf2f(Ws[(size_t)(r0 + rr) * C + c0 + cc + j]);
    } else {
        float4 v = *(const float4*)((const float*)W + (size_t)(r0 + rr) * C + c0 + cc);
        lds[rr][cc + 0] = v.x; lds[rr][cc + 1] = v.y; lds[rr][cc + 2] = v.z; lds[rr][cc + 3] = v.w;
    }
    __syncthreads();
    ushort4 o;
    o.x = f2bf(lds[cc + 0][rr]); o.y = f2bf(lds[cc + 1][rr]);
    o.z = f2bf(lds[cc + 2][rr]); o.w = f2bf(lds[cc + 3][rr]);
    int n = c0 + rr, k = r0 + cc;
    *(ushort4*)(T + ((((size_t)(n >> 4) * (R >> 3) + (k >> 3)) * 16 + (n & 15)) << 3) + (k & 7)) = o;
}

// ---- QKV GEMM (R6 structure). R12 change: V output written in MFMA32 B-frag
// PACKED layout [bh][s/16][lane=d+32*((s>>3)&1)][s&7] so attn's loadV becomes a
// 1KB-contiguous per-lane load instead of a 32-line gather.
__global__ __launch_bounds__(256) void qkv_gemm(
    const void* __restrict__ Q, const void* __restrict__ K, const void* __restrict__ V,
    const ushort* __restrict__ Wt, const float* __restrict__ biasf,
    ushort* __restrict__ qh, ushort* __restrict__ kh, ushort* __restrict__ vT)
{
    int isbf = detect_isbf((const ushort*)Q);
    int y = blockIdx.y;
    const void* X = (y == 0) ? Q : (y == 1) ? K : V;
    int wave = threadIdx.x >> 6, lane = threadIdx.x & 63;
    int l16 = lane & 15, quad = lane >> 4;
    int m0 = blockIdx.x * 16;           // grid.x = 256
    int n0 = wave * 64;
    const ushort* W = Wt + (size_t)y * (256 * 512);

    auto loadA = [&](int ks, bf16x8* a) {
        if (isbf) {
            *a = *(const bf16x8*)((const ushort*)X + (size_t)(m0 + l16) * 512 + ks + quad * 8);
        } else {
            const float* p = (const float*)X + (size_t)(m0 + l16) * 512 + ks + quad * 8;
            float4 f0 = *(const float4*)p, f1 = *(const float4*)(p + 4);
            union { uint u[4]; bf16x8 v; } cv;
            cv.u[0] = cvt_pk_bf16(f0.x, f0.y);
            cv.u[1] = cvt_pk_bf16(f0.z, f0.w);
            cv.u[2] = cvt_pk_bf16(f1.x, f1.y);
            cv.u[3] = cvt_pk_bf16(f1.z, f1.w);
            *a = cv.v;
        }
    };
    auto loadB = [&](int ks, bf16x8* b) {
        #pragma unroll
        for (int j = 0; j < 4; ++j)
            b[j] = *(const bf16x8*)(W + (((size_t)((n0 >> 4) + j) * 64 + (ks >> 3) + quad) * 16 + l16) * 8);
    };

    f32x4 acc[4] = {};
    bf16x8 aC, bC[4], aN, bN[4];
    loadA(0, &aC); loadB(0, bC);
    for (int ks = 0; ks < 512; ks += 32) {
        if (ks + 32 < 512) { loadA(ks + 32, &aN); loadB(ks + 32, bN); }
        #pragma unroll
        for (int j = 0; j < 4; ++j)
            acc[j] = MFMA(aC, bC[j], acc[j], 0, 0, 0);
        aC = aN;
        #pragma unroll
        for (int j = 0; j < 4; ++j) bC[j] = bN[j];
    }
    if (y < 2) {
        ushort* out = (y == 0) ? qh : kh;
        #pragma unroll
        for (int j = 0; j < 4; ++j) {
            int n = n0 + 16 * j + l16;
            float bs = biasf[y * 256 + n];
            int h = n >> 5, d = n & 31;
            #pragma unroll
            for (int r = 0; r < 4; ++r) {
                int rg = m0 + quad * 4 + r;
                int bb = rg >> 11, ss = rg & 2047;
                out[((((size_t)bb * NH + h) * S_ + ss) << 5) + d] = f2bf(acc[j][r] + bs);
            }
        }
    } else {
        int rg0 = m0 + quad * 4;
        int bb = rg0 >> 11;
        int tt = (rg0 & 2047) >> 4;            // 16-row tile index (quad*4+r < 16)
        int sb = quad >> 1;                    // (s>>3)&1
        int jb = (quad & 1) * 4;               // s&7 base for r=0..3
        #pragma unroll
        for (int j = 0; j < 4; ++j) {
            int n = n0 + 16 * j + l16;
            float bs = biasf[2 * 256 + n];
            int h = n >> 5, d = n & 31;
            ushort4 o;
            o.x = f2bf(acc[j][0] + bs); o.y = f2bf(acc[j][1] + bs);
            o.z = f2bf(acc[j][2] + bs); o.w = f2bf(acc[j][3] + bs);
            *(ushort4*)(vT + ((((size_t)(bb * NH + h) * 128 + tt) * 64 + d + 32 * sb) << 3) + jb) = o;
        }
    }
}

// ---- attention. R12: (a) V loads from the packed frag layout (contiguous,
// no gather); (b) substep widened to 64 k-columns (16 substeps instead of 32)
// to amortize the ~fixed per-substep stall; mask LDS tile 32x64 (pad 66),
// double-buffered per wave. In-register softmax (T12) unchanged from R8.
__global__ __launch_bounds__(256) void attn(
    const ushort* __restrict__ qh, const ushort* __restrict__ kh,
    const ushort* __restrict__ vT, const void* __restrict__ maskp,
    float* __restrict__ pO, float* __restrict__ pl)
{
    __shared__ float ldsM[4][2][32][66];   // 67.6 KB
    int isbf;
    {
        int lane = threadIdx.x & 63;
        ushort u = ((const ushort*)maskp)[lane];
        int e = (u >> 7) & 0xFF;
        unsigned long long m = __ballot(e >= 100 && e <= 133);
        isbf = __popcll(m) >= 58;
    }
    int wave = threadIdx.x >> 6, lane = threadIdx.x & 63;
    int l31 = lane & 31, hi = lane >> 5;
    int wid = blockIdx.x * 4 + wave;        // 2048 waves
    int chunk = wid & 1, qt32 = (wid >> 1) & 63, bh = wid >> 7;
    int b = bh >> 3;
    int q0 = qt32 * 32;
    const ushort* qb = qh + (size_t)bh * S_ * HD;
    const ushort* kb = kh + (size_t)bh * S_ * HD;
    const ushort* vbp = vT + (size_t)bh * 65536;     // packed [t=s/16][lane][8]
    const ushort* mbb = (const ushort*)maskp + (size_t)b * S_ * S_;
    const float*  mbf = (const float*)maskp  + (size_t)b * S_ * S_;

    bf16x8 bq0 = *(const bf16x8*)(qb + (size_t)(q0 + l31) * HD + hi * 8);
    bf16x8 bq1 = *(const bf16x8*)(qb + (size_t)(q0 + l31) * HD + 16 + hi * 8);

    f32x16 O = {0,0,0,0,0,0,0,0,0,0,0,0,0,0,0,0};
    const f32x16 Z = {0,0,0,0,0,0,0,0,0,0,0,0,0,0,0,0};
    float lsum = 0.0f;

    int srow = lane >> 4;            // 0..3
    int scol = (lane & 15) * 4;      // 0..60
    float4 g[8];                     // in-flight 32x64 mask tile

    auto loadMg = [&](int k0) {
        if (isbf) {
            #pragma unroll
            for (int i = 0; i < 8; ++i) {
                ushort4 u = *(const ushort4*)(mbb + (size_t)(q0 + i * 4 + srow) * S_ + k0 + scol);
                float4 f; f.x = bf2f(u.x); f.y = bf2f(u.y); f.z = bf2f(u.z); f.w = bf2f(u.w);
                g[i] = f;
            }
        } else {
            #pragma unroll
            for (int i = 0; i < 8; ++i)
                g[i] = *(const float4*)(mbf + (size_t)(q0 + i * 4 + srow) * S_ + k0 + scol);
        }
    };
    auto writeM = [&](int buf) {
        #pragma unroll
        for (int i = 0; i < 8; ++i) {
            ldsM[wave][buf][i * 4 + srow][scol + 0] = g[i].x;
            ldsM[wave][buf][i * 4 + srow][scol + 1] = g[i].y;
            ldsM[wave][buf][i * 4 + srow][scol + 2] = g[i].z;
            ldsM[wave][buf][i * 4 + srow][scol + 3] = g[i].w;
        }
    };
    auto loadK = [&](int k0, bf16x8* K4) {      // two 32-k' A-tiles (4 frags)
        K4[0] = *(const bf16x8*)(kb + (size_t)(k0 + l31) * HD + hi * 8);
        K4[1] = *(const bf16x8*)(kb + (size_t)(k0 + l31) * HD + 16 + hi * 8);
        K4[2] = *(const bf16x8*)(kb + (size_t)(k0 + 32 + l31) * HD + hi * 8);
        K4[3] = *(const bf16x8*)(kb + (size_t)(k0 + 32 + l31) * HD + 16 + hi * 8);
    };
    auto loadV = [&](int k0, bf16x8* V4) {      // four 16-k B-frags, packed
        int t0 = k0 >> 4;
        #pragma unroll
        for (int i = 0; i < 4; ++i)
            V4[i] = *(const bf16x8*)(vbp + (((size_t)(t0 + i) * 64 + lane) << 3));
    };

    int kbase = chunk * 1024;

    auto sub = [&](int buf, bf16x8* Kc, bf16x8* Vc, bf16x8* Kn, bf16x8* Vn, int t) {
        // prefetch K/V for wide-tile t+1 (clamped; redundant at tail, unread)
        int ktn = kbase + ((t + 1 < 16) ? (t + 1) : 15) * 64;
        loadK(ktn, Kn); loadV(ktn, Vn);
        // mask regs for this tile (S^T acc layout: row k'=(r&3)+8*(r>>2)+4*hi, col q=l31)
        float Mr0[16], Mr1[16];
        #pragma unroll
        for (int r = 0; r < 16; ++r) {
            int c = (r & 3) + ((r >> 2) << 3) + (hi << 2);
            Mr0[r] = ldsM[wave][buf][l31][c];
            Mr1[r] = ldsM[wave][buf][l31][32 + c];
        }
        // QK^T swapped, both 32-k' halves
        f32x16 S0 = MFMA32(Kc[0], bq0, Z, 0, 0, 0);
        S0 = MFMA32(Kc[1], bq1, S0, 0, 0, 0);
        f32x16 S1 = MFMA32(Kc[2], bq0, Z, 0, 0, 0);
        S1 = MFMA32(Kc[3], bq1, S1, 0, 0, 0);
        // stage mask tile t+1 into LDS (globals issued last substep), fetch t+2
        writeM(buf ^ 1);
        int ktm = kbase + ((t + 2 < 16) ? (t + 2) : 15) * 64;
        loadMg(ktm);
        // softmax in registers (exp in place)
        #pragma unroll
        for (int r = 0; r < 16; ++r) {
            S0[r] = __expf(fmaf(S0[r], 0.0625f, Mr0[r]));
            lsum += S0[r];
            S1[r] = __expf(fmaf(S1[r], 0.0625f, Mr1[r]));
            lsum += S1[r];
        }
        // P -> bf16 A-frags via cvt_pk + permlane32_swap (DST = low k'-group)
        union { uint u[4]; bf16x8 v; } pa0, pa1, pa2, pa3;
        {
            uint u0 = cvt_pk_bf16(S0[0], S0[1]),  w0 = cvt_pk_bf16(S0[4], S0[5]);
            uint u1 = cvt_pk_bf16(S0[2], S0[3]),  w1 = cvt_pk_bf16(S0[6], S0[7]);
            asm volatile("v_permlane32_swap_b32 %0, %1" : "+v"(u0), "+v"(w0));
            asm volatile("v_permlane32_swap_b32 %0, %1" : "+v"(u1), "+v"(w1));
            pa0.u[0] = u0; pa0.u[1] = u1; pa0.u[2] = w0; pa0.u[3] = w1;
            uint u2 = cvt_pk_bf16(S0[8], S0[9]),   w2 = cvt_pk_bf16(S0[12], S0[13]);
            uint u3 = cvt_pk_bf16(S0[10], S0[11]), w3 = cvt_pk_bf16(S0[14], S0[15]);
            asm volatile("v_permlane32_swap_b32 %0, %1" : "+v"(u2), "+v"(w2));
            asm volatile("v_permlane32_swap_b32 %0, %1" : "+v"(u3), "+v"(w3));
            pa1.u[0] = u2; pa1.u[1] = u3; pa1.u[2] = w2; pa1.u[3] = w3;
            uint u4 = cvt_pk_bf16(S1[0], S1[1]),  w4 = cvt_pk_bf16(S1[4], S1[5]);
            uint u5 = cvt_pk_bf16(S1[2], S1[3]),  w5 = cvt_pk_bf16(S1[6], S1[7]);
            asm volatile("v_permlane32_swap_b32 %0, %1" : "+v"(u4), "+v"(w4));
            asm volatile("v_permlane32_swap_b32 %0, %1" : "+v"(u5), "+v"(w5));
            pa2.u[0] = u4; pa2.u[1] = u5; pa2.u[2] = w4; pa2.u[3] = w5;
            uint u6 = cvt_pk_bf16(S1[8], S1[9]),   w6 = cvt_pk_bf16(S1[12], S1[13]);
            uint u7 = cvt_pk_bf16(S1[10], S1[11]), w7 = cvt_pk_bf16(S1[14], S1[15]);
            asm volatile("v_permlane32_swap_b32 %0, %1" : "+v"(u6), "+v"(w6));
            asm volatile("v_permlane32_swap_b32 %0, %1" : "+v"(u7), "+v"(w7));
            pa3.u[0] = u6; pa3.u[1] = u7; pa3.u[2] = w6; pa3.u[3] = w7;
        }
        // PV
        O = MFMA32(pa0.v, Vc[0], O, 0, 0, 0);
        O = MFMA32(pa1.v, Vc[1], O, 0, 0, 0);
        O = MFMA32(pa2.v, Vc[2], O, 0, 0, 0);
        O = MFMA32(pa3.v, Vc[3], O, 0, 0, 0);
    };

    bf16x8 KA[4], VA[4], KB[4], VB[4];
    loadK(kbase, KA); loadV(kbase, VA);
    loadMg(kbase); writeM(0);
    loadMg(kbase + 64);
    for (int t = 0; t < 16; t += 2) {
        sub(0, KA, VA, KB, VB, t);
        sub(1, KB, VB, KA, VA, t + 1);
    }

    // epilogue: row sums + pO/pl in the R6 layout
    float tot = lsum + __shfl_xor(lsum, 32, 64);
    int wid16_0 = ((bh * 128) + qt32 * 2 + 0) * 2 + chunk;
    int wid16_1 = ((bh * 128) + qt32 * 2 + 1) * 2 + chunk;
    if (lane < 32) {
        int q = l31;
        int w16 = (q < 16) ? wid16_0 : wid16_1;
        pl[w16 * 16 + (q & 15)] = tot;
    }
    #pragma unroll
    for (int r = 0; r < 16; ++r) {
        int q = (r & 3) + ((r >> 2) << 3) + (hi << 2);
        int w16 = (q < 16) ? wid16_0 : wid16_1;
        pO[(size_t)w16 * 512 + (q & 15) * 32 + l31] = O[r];
    }
}

// ---- out projection (R6 structure, unchanged): 16-row m-tiles, packed-B, cvt_pk
__global__ __launch_bounds__(256) void out_proj(
    const float* __restrict__ pO, const float* __restrict__ pl,
    const ushort* __restrict__ Wot, const float* __restrict__ biasf,
    float* __restrict__ out)
{
    int wave = threadIdx.x >> 6, lane = threadIdx.x & 63;
    int l16 = lane & 15, quad = lane >> 4;
    int m0 = (blockIdx.x >> 1) * 16;                  // grid = 512
    int n0 = (blockIdx.x & 1) * 256 + wave * 64;
    f32x4 acc[4] = {};
    for (int ks = 0; ks < 256; ks += 32) {
        int h = ks >> 5;
        bf16x8 a, b[4];
        {
            int row = m0 + l16;
            int bb = row >> 11, s = row & 2047;
            int qt = s >> 4, r16 = s & 15;
            int wid0 = ((bb * NH + h) << 8) | (qt << 1);
            const float* p0 = pO + (size_t)wid0 * 512 + r16 * 32 + quad * 8;
            float4 x0 = *(const float4*)p0,         x1 = *(const float4*)(p0 + 4);
            float4 y0 = *(const float4*)(p0 + 512), y1 = *(const float4*)(p0 + 516);
            float il = 1.0f / (pl[wid0 * 16 + r16] + pl[(wid0 + 1) * 16 + r16]);
            union { uint u[4]; bf16x8 v; } cv;
            cv.u[0] = cvt_pk_bf16((x0.x + y0.x) * il, (x0.y + y0.y) * il);
            cv.u[1] = cvt_pk_bf16((x0.z + y0.z) * il, (x0.w + y0.w) * il);
            cv.u[2] = cvt_pk_bf16((x1.x + y1.x) * il, (x1.y + y1.y) * il);
            cv.u[3] = cvt_pk_bf16((x1.z + y1.z) * il, (x1.w + y1.w) * il);
            a = cv.v;
        }
        #pragma unroll
        for (int j = 0; j < 4; ++j)
            b[j] = *(const bf16x8*)(Wot + (((size_t)((n0 >> 4) + j) * 32 + (ks >> 3) + quad) * 16 + l16) * 8);
        #pragma unroll
        for (int j = 0; j < 4; ++j)
            acc[j] = MFMA(a, b[j], acc[j], 0, 0, 0);
    }
    #pragma unroll
    for (int j = 0; j < 4; ++j) {
        int n = n0 + 16 * j + l16;
        float bs = biasf[768 + n];
        #pragma unroll
        for (int r = 0; r < 4; ++r) {
            int rg = m0 + quad * 4 + r;
            out[(size_t)rg * DM + n] = acc[j][r] + bs;
        }
    }
}

extern "C" void kernel_launch(void* const* d_in, const int* in_sizes, int n_in,
                              void* d_out, int out_size, void* d_ws, size_t ws_size,
                              hipStream_t stream)
{
    const void* V    = d_in[0];
    const void* Q    = d_in[1];
    const void* K    = d_in[2];
    const void* mask = d_in[3];
    const void* Wq = d_in[4];  const void* bq = d_in[5];
    const void* Wk = d_in[6];  const void* bk = d_in[7];
    const void* Wv = d_in[8];  const void* bv = d_in[9];
    const void* Wo = d_in[10]; const void* bo = d_in[11];
    float* out = (float*)d_out;

    char* ws = (char*)d_ws;
    float*  biasf = (float*)ws;                    // 1280 fp32
    ushort* Wt  = (ushort*)(ws + 8192);            // 393,216 ushorts
    ushort* Wot = Wt  + 393216;                    // 131,072
    ushort* qh  = Wot + 131072;                    // 1,048,576 each (2 MB)
    ushort* kh  = qh  + 1048576;
    ushort* vT  = kh  + 1048576;
    float*  pO  = (float*)(vT + 1048576);          // 4096 x 512 fp32 (8.4 MB)
    float*  pl  = pO + 4096 * 512;                 // 65,536 fp32

    transpose_w<<<513, 256, 0, stream>>>(Wq, Wk, Wv, Wo, bq, bk, bv, bo,
                                         (const ushort*)Q, Wt, Wot, biasf);
    qkv_gemm<<<dim3(256, 3), 256, 0, stream>>>(Q, K, V, Wt, biasf, qh, kh, vT);
    attn<<<512, 256, 0, stream>>>(qh, kh, vT, mask, pO, pl);
    out_proj<<<512, 256, 0, stream>>>(pO, pl, Wot, biasf, out);
}

// Round 10
// 173.471 us; speedup vs baseline: 1.0569x; 1.0222x over previous
//
#include <hip/hip_runtime.h>

typedef __attribute__((ext_vector_type(8))) short bf16x8;
typedef __attribute__((ext_vector_type(4))) float f32x4;
typedef __attribute__((ext_vector_type(16))) float f32x16;

#define B_  2
#define S_  2048
#define DM  512
#define KD  256
#define HD  32
#define NH  8

__device__ __forceinline__ float bf2f(ushort u) {
    return __uint_as_float(((uint)u) << 16);
}
__device__ __forceinline__ ushort f2bf(float f) {
    uint x = __float_as_uint(f);
    return (ushort)((x + 0x7fffu + ((x >> 16) & 1u)) >> 16);  // RNE
}
// gfx950 packed f32->bf16 (RNE), 1 instr per 2 elements
__device__ __forceinline__ uint cvt_pk_bf16(float lo, float hi) {
    uint r;
    asm("v_cvt_pk_bf16_f32 %0, %1, %2" : "=v"(r) : "v"(lo), "v"(hi));
    return r;
}
#define MFMA __builtin_amdgcn_mfma_f32_16x16x32_bf16
#define MFMA32 __builtin_amdgcn_mfma_f32_32x32x16_bf16

__device__ __forceinline__ int detect_isbf(const ushort* __restrict__ q)
{
    int lane = threadIdx.x & 63;
    int e = (q[lane] >> 7) & 0xFF;
    unsigned long long m = __ballot(e >= 100 && e <= 133);
    return __popcll(m) >= 58;
}

// ---- W transposes + biases; output in PACKED fragment layout [n/16][k/8][16][8]
__global__ __launch_bounds__(256) void transpose_w(
    const void* __restrict__ Wq, const void* __restrict__ Wk, const void* __restrict__ Wv,
    const void* __restrict__ Wo,
    const void* __restrict__ bq, const void* __restrict__ bk,
    const void* __restrict__ bv, const void* __restrict__ bo,
    const ushort* __restrict__ qsrc,
    ushort* __restrict__ Wt, ushort* __restrict__ Wot, float* __restrict__ biasf)
{
    int isbf = detect_isbf(qsrc);
    int bid = blockIdx.x;
    if (bid >= 512) {
        for (int i = threadIdx.x; i < 1280; i += 256) {
            const void* bp; int off;
            if (i < 256)      { bp = bq; off = i; }
            else if (i < 512) { bp = bk; off = i - 256; }
            else if (i < 768) { bp = bv; off = i - 512; }
            else              { bp = bo; off = i - 768; }
            biasf[i] = isbf ? bf2f(((const ushort*)bp)[off]) : ((const float*)bp)[off];
        }
        return;
    }
    const void* W; int R, C; ushort* T;
    int m = bid >> 7, tix = bid & 127;
    if (m < 3) { W = (m == 0) ? Wq : (m == 1) ? Wk : Wv; R = 512; C = 256; T = Wt + m * 131072; }
    else       { W = Wo; R = 256; C = 512; T = Wot; }
    int tilesPerRow = C >> 5;
    int r0 = (tix / tilesPerRow) * 32, c0 = (tix % tilesPerRow) * 32;
    __shared__ float lds[32][33];
    int t = threadIdx.x;
    int rr = t >> 3, cc = (t & 7) * 4;
    if (isbf) {
        const ushort* Ws = (const ushort*)W;
        #pragma unroll
        for (int j = 0; j < 4; ++j) lds[rr][cc + j] = bf2f(Ws[(size_t)(r0 + rr) * C + c0 + cc + j]);
    } else {
        float4 v = *(const float4*)((const float*)W + (size_t)(r0 + rr) * C + c0 + cc);
        lds[rr][cc + 0] = v.x; lds[rr][cc + 1] = v.y; lds[rr][cc + 2] = v.z; lds[rr][cc + 3] = v.w;
    }
    __syncthreads();
    ushort4 o;
    o.x = f2bf(lds[cc + 0][rr]); o.y = f2bf(lds[cc + 1][rr]);
    o.z = f2bf(lds[cc + 2][rr]); o.w = f2bf(lds[cc + 3][rr]);
    int n = c0 + rr, k = r0 + cc;
    *(ushort4*)(T + ((((size_t)(n >> 4) * (R >> 3) + (k >> 3)) * 16 + (n & 15)) << 3) + (k & 7)) = o;
}

// ---- QKV GEMM (R9 version, unchanged): 16-row m-tiles, packed-B, cvt_pk;
// V written in MFMA32 B-frag packed layout [bh][s/16][d+32*((s>>3)&1)][s&7].
__global__ __launch_bounds__(256) void qkv_gemm(
    const void* __restrict__ Q, const void* __restrict__ K, const void* __restrict__ V,
    const ushort* __restrict__ Wt, const float* __restrict__ biasf,
    ushort* __restrict__ qh, ushort* __restrict__ kh, ushort* __restrict__ vT)
{
    int isbf = detect_isbf((const ushort*)Q);
    int y = blockIdx.y;
    const void* X = (y == 0) ? Q : (y == 1) ? K : V;
    int wave = threadIdx.x >> 6, lane = threadIdx.x & 63;
    int l16 = lane & 15, quad = lane >> 4;
    int m0 = blockIdx.x * 16;           // grid.x = 256
    int n0 = wave * 64;
    const ushort* W = Wt + (size_t)y * (256 * 512);

    auto loadA = [&](int ks, bf16x8* a) {
        if (isbf) {
            *a = *(const bf16x8*)((const ushort*)X + (size_t)(m0 + l16) * 512 + ks + quad * 8);
        } else {
            const float* p = (const float*)X + (size_t)(m0 + l16) * 512 + ks + quad * 8;
            float4 f0 = *(const float4*)p, f1 = *(const float4*)(p + 4);
            union { uint u[4]; bf16x8 v; } cv;
            cv.u[0] = cvt_pk_bf16(f0.x, f0.y);
            cv.u[1] = cvt_pk_bf16(f0.z, f0.w);
            cv.u[2] = cvt_pk_bf16(f1.x, f1.y);
            cv.u[3] = cvt_pk_bf16(f1.z, f1.w);
            *a = cv.v;
        }
    };
    auto loadB = [&](int ks, bf16x8* b) {
        #pragma unroll
        for (int j = 0; j < 4; ++j)
            b[j] = *(const bf16x8*)(W + (((size_t)((n0 >> 4) + j) * 64 + (ks >> 3) + quad) * 16 + l16) * 8);
    };

    f32x4 acc[4] = {};
    bf16x8 aC, bC[4], aN, bN[4];
    loadA(0, &aC); loadB(0, bC);
    for (int ks = 0; ks < 512; ks += 32) {
        if (ks + 32 < 512) { loadA(ks + 32, &aN); loadB(ks + 32, bN); }
        #pragma unroll
        for (int j = 0; j < 4; ++j)
            acc[j] = MFMA(aC, bC[j], acc[j], 0, 0, 0);
        aC = aN;
        #pragma unroll
        for (int j = 0; j < 4; ++j) bC[j] = bN[j];
    }
    if (y < 2) {
        ushort* out = (y == 0) ? qh : kh;
        #pragma unroll
        for (int j = 0; j < 4; ++j) {
            int n = n0 + 16 * j + l16;
            float bs = biasf[y * 256 + n];
            int h = n >> 5, d = n & 31;
            #pragma unroll
            for (int r = 0; r < 4; ++r) {
                int rg = m0 + quad * 4 + r;
                int bb = rg >> 11, ss = rg & 2047;
                out[((((size_t)bb * NH + h) * S_ + ss) << 5) + d] = f2bf(acc[j][r] + bs);
            }
        }
    } else {
        int rg0 = m0 + quad * 4;
        int bb = rg0 >> 11;
        int tt = (rg0 & 2047) >> 4;
        int sb = quad >> 1;
        int jb = (quad & 1) * 4;
        #pragma unroll
        for (int j = 0; j < 4; ++j) {
            int n = n0 + 16 * j + l16;
            float bs = biasf[2 * 256 + n];
            int h = n >> 5, d = n & 31;
            ushort4 o;
            o.x = f2bf(acc[j][0] + bs); o.y = f2bf(acc[j][1] + bs);
            o.z = f2bf(acc[j][2] + bs); o.w = f2bf(acc[j][3] + bs);
            *(ushort4*)(vT + ((((size_t)(bb * NH + h) * 128 + tt) * 64 + d + 32 * sb) << 3) + jb) = o;
        }
    }
}

// ---- attention. R13: HEAD-GROUPED blocks — 512 threads = 8 waves = the 8
// heads of one (b, 32-q-tile, k-chunk). The mask tile (shared by all heads,
// previously re-read 8x from L3 = 268 MB logical, the L3-BW wall) is staged
// ONCE per block into a small double-buffered LDS tile [2][32][33] and read
// conflict-free by every wave -> mask traffic drops to 33.5 MB. Per-wave
// inner structure = R8's in-register softmax (T12) + R9's packed-V loads;
// 32-k substeps, one __syncthreads per substep.
__global__ __launch_bounds__(512) void attn(
    const ushort* __restrict__ qh, const ushort* __restrict__ kh,
    const ushort* __restrict__ vT, const void* __restrict__ maskp,
    float* __restrict__ pO, float* __restrict__ pl, int chsh)
{
    __shared__ float ldsM[2][32][33];   // 8.4 KB
    int isbf;
    {
        int lane = threadIdx.x & 63;
        ushort u = ((const ushort*)maskp)[lane];
        int e = (u >> 7) & 0xFF;
        unsigned long long m = __ballot(e >= 100 && e <= 133);
        isbf = __popcll(m) >= 58;
    }
    int tid = threadIdx.x;
    int wave = tid >> 6, lane = tid & 63;
    int l31 = lane & 31, hi = lane >> 5;
    int CH = 1 << chsh;
    int bid = blockIdx.x;                    // grid = 128 << chsh
    int chunk = bid & (CH - 1);
    int qt32 = (bid >> chsh) & 63;
    int b = bid >> (chsh + 6);
    int h = wave;                            // one head per wave
    int bh = b * NH + h;
    int q0 = qt32 * 32;
    int klen = 2048 >> chsh;
    int kbase = chunk * klen;
    int NT = klen >> 5;                      // 32-k substeps

    const ushort* qb = qh + (size_t)bh * S_ * HD;
    const ushort* kb = kh + (size_t)bh * S_ * HD;
    const ushort* vbp = vT + (size_t)bh * 65536;     // packed [s/16][lane][8]
    const ushort* mbb = (const ushort*)maskp + (size_t)b * S_ * S_;
    const float*  mbf = (const float*)maskp  + (size_t)b * S_ * S_;

    bf16x8 bq0 = *(const bf16x8*)(qb + (size_t)(q0 + l31) * HD + hi * 8);
    bf16x8 bq1 = *(const bf16x8*)(qb + (size_t)(q0 + l31) * HD + 16 + hi * 8);

    f32x16 O = {0,0,0,0,0,0,0,0,0,0,0,0,0,0,0,0};
    const f32x16 Z = {0,0,0,0,0,0,0,0,0,0,0,0,0,0,0,0};
    float lsum = 0.0f;

    // mask staging: 512 threads, one float2 each: row=tid>>4, col=(tid&15)*2
    int srow = tid >> 4, scol = (tid & 15) * 2;
    float2 g;

    auto loadMg = [&](int k0) {
        if (isbf) {
            ushort2 u = *(const ushort2*)(mbb + (size_t)(q0 + srow) * S_ + k0 + scol);
            g.x = bf2f(u.x); g.y = bf2f(u.y);
        } else {
            g = *(const float2*)(mbf + (size_t)(q0 + srow) * S_ + k0 + scol);
        }
    };
    auto writeM = [&](int buf) {
        ldsM[buf][srow][scol]     = g.x;
        ldsM[buf][srow][scol + 1] = g.y;
    };
    auto loadK = [&](int k0, bf16x8* K2) {
        K2[0] = *(const bf16x8*)(kb + (size_t)(k0 + l31) * HD + hi * 8);
        K2[1] = *(const bf16x8*)(kb + (size_t)(k0 + l31) * HD + 16 + hi * 8);
    };
    auto loadV = [&](int k0, bf16x8* V2) {
        int t0 = k0 >> 4;
        V2[0] = *(const bf16x8*)(vbp + (((size_t)t0 * 64 + lane) << 3));
        V2[1] = *(const bf16x8*)(vbp + (((size_t)(t0 + 1) * 64 + lane) << 3));
    };

    auto sub = [&](int buf, bf16x8* Kc, bf16x8* Vc, bf16x8* Kn, bf16x8* Vn, int t) {
        // mask regs for tile t (S^T acc: col q=l31, row k'=(r&3)+8*(r>>2)+4*hi)
        float Mreg[16];
        #pragma unroll
        for (int r = 0; r < 16; ++r)
            Mreg[r] = ldsM[buf][l31][(r & 3) + ((r >> 2) << 3) + (hi << 2)];
        // prefetch K/V for t+1 (clamped; redundant at tail)
        int ktn = kbase + ((t + 1 < NT) ? (t + 1) : (NT - 1)) * 32;
        loadK(ktn, Kn); loadV(ktn, Vn);
        // QK^T swapped
        f32x16 S = MFMA32(Kc[0], bq0, Z, 0, 0, 0);
        S = MFMA32(Kc[1], bq1, S, 0, 0, 0);
        // stage mask tile t+1 (g loaded one substep ago), issue load for t+2
        writeM(buf ^ 1);
        loadMg(kbase + ((t + 2 < NT) ? (t + 2) : (NT - 1)) * 32);
        // softmax in registers
        float p[16];
        #pragma unroll
        for (int r = 0; r < 16; ++r) {
            p[r] = __expf(fmaf(S[r], 0.0625f, Mreg[r]));
            lsum += p[r];
        }
        // P -> bf16 A-frags via cvt_pk + permlane32_swap (DST = low k'-group)
        union { uint u[4]; bf16x8 v; } pa0, pa1;
        {
            uint u0 = cvt_pk_bf16(p[0], p[1]),  w0 = cvt_pk_bf16(p[4], p[5]);
            uint u1 = cvt_pk_bf16(p[2], p[3]),  w1 = cvt_pk_bf16(p[6], p[7]);
            asm volatile("v_permlane32_swap_b32 %0, %1" : "+v"(u0), "+v"(w0));
            asm volatile("v_permlane32_swap_b32 %0, %1" : "+v"(u1), "+v"(w1));
            pa0.u[0] = u0; pa0.u[1] = u1; pa0.u[2] = w0; pa0.u[3] = w1;
            uint u2 = cvt_pk_bf16(p[8], p[9]),   w2 = cvt_pk_bf16(p[12], p[13]);
            uint u3 = cvt_pk_bf16(p[10], p[11]), w3 = cvt_pk_bf16(p[14], p[15]);
            asm volatile("v_permlane32_swap_b32 %0, %1" : "+v"(u2), "+v"(w2));
            asm volatile("v_permlane32_swap_b32 %0, %1" : "+v"(u3), "+v"(w3));
            pa1.u[0] = u2; pa1.u[1] = u3; pa1.u[2] = w2; pa1.u[3] = w3;
        }
        // PV
        O = MFMA32(pa0.v, Vc[0], O, 0, 0, 0);
        O = MFMA32(pa1.v, Vc[1], O, 0, 0, 0);
        __syncthreads();   // tile t fully read; tile t+1 writes visible
    };

    bf16x8 KA[2], VA[2], KB[2], VB[2];
    loadK(kbase, KA); loadV(kbase, VA);
    loadMg(kbase); writeM(0);
    loadMg(kbase + ((1 < NT) ? 32 : 0));
    __syncthreads();
    for (int t = 0; t < NT; t += 2) {
        sub(0, KA, VA, KB, VB, t);
        sub(1, KB, VB, KA, VA, t + 1);
    }

    // epilogue: row sums + pO/pl (CH-chunk layout; out_proj combines CH)
    float tot = lsum + __shfl_xor(lsum, 32, 64);
    int wid16_0 = (((bh << 7) + qt32 * 2 + 0) << chsh) + chunk;
    int wid16_1 = (((bh << 7) + qt32 * 2 + 1) << chsh) + chunk;
    if (lane < 32) {
        int q = l31;
        int w16 = (q < 16) ? wid16_0 : wid16_1;
        pl[w16 * 16 + (q & 15)] = tot;
    }
    #pragma unroll
    for (int r = 0; r < 16; ++r) {
        int q = (r & 3) + ((r >> 2) << 3) + (hi << 2);
        int w16 = (q < 16) ? wid16_0 : wid16_1;
        pO[(size_t)w16 * 512 + (q & 15) * 32 + l31] = O[r];
    }
}

// ---- out projection: 16-row m-tiles, packed-B, cvt_pk; combines CH chunks
__global__ __launch_bounds__(256) void out_proj(
    const float* __restrict__ pO, const float* __restrict__ pl,
    const ushort* __restrict__ Wot, const float* __restrict__ biasf,
    float* __restrict__ out, int chsh)
{
    int wave = threadIdx.x >> 6, lane = threadIdx.x & 63;
    int l16 = lane & 15, quad = lane >> 4;
    int m0 = (blockIdx.x >> 1) * 16;                  // grid = 512
    int n0 = (blockIdx.x & 1) * 256 + wave * 64;
    int CH = 1 << chsh;
    f32x4 acc[4] = {};
    for (int ks = 0; ks < 256; ks += 32) {
        int h = ks >> 5;
        bf16x8 a, b[4];
        {
            int row = m0 + l16;
            int bb = row >> 11, s = row & 2047;
            int qt = s >> 4, r16 = s & 15;
            int wid0 = (((bb * NH + h) << 7) + qt) << chsh;
            float s8[8] = {0, 0, 0, 0, 0, 0, 0, 0};
            float lacc = 0.0f;
            for (int cc = 0; cc < CH; ++cc) {
                const float* p = pO + ((size_t)(wid0 + cc) << 9) + r16 * 32 + quad * 8;
                float4 u0 = *(const float4*)p, u1 = *(const float4*)(p + 4);
                s8[0] += u0.x; s8[1] += u0.y; s8[2] += u0.z; s8[3] += u0.w;
                s8[4] += u1.x; s8[5] += u1.y; s8[6] += u1.z; s8[7] += u1.w;
                lacc += pl[(wid0 + cc) * 16 + r16];
            }
            float il = 1.0f / lacc;
            union { uint u[4]; bf16x8 v; } cv;
            cv.u[0] = cvt_pk_bf16(s8[0] * il, s8[1] * il);
            cv.u[1] = cvt_pk_bf16(s8[2] * il, s8[3] * il);
            cv.u[2] = cvt_pk_bf16(s8[4] * il, s8[5] * il);
            cv.u[3] = cvt_pk_bf16(s8[6] * il, s8[7] * il);
            a = cv.v;
        }
        #pragma unroll
        for (int j = 0; j < 4; ++j)
            b[j] = *(const bf16x8*)(Wot + (((size_t)((n0 >> 4) + j) * 32 + (ks >> 3) + quad) * 16 + l16) * 8);
        #pragma unroll
        for (int j = 0; j < 4; ++j)
            acc[j] = MFMA(a, b[j], acc[j], 0, 0, 0);
    }
    #pragma unroll
    for (int j = 0; j < 4; ++j) {
        int n = n0 + 16 * j + l16;
        float bs = biasf[768 + n];
        #pragma unroll
        for (int r = 0; r < 4; ++r) {
            int rg = m0 + quad * 4 + r;
            out[(size_t)rg * DM + n] = acc[j][r] + bs;
        }
    }
}

extern "C" void kernel_launch(void* const* d_in, const int* in_sizes, int n_in,
                              void* d_out, int out_size, void* d_ws, size_t ws_size,
                              hipStream_t stream)
{
    const void* V    = d_in[0];
    const void* Q    = d_in[1];
    const void* K    = d_in[2];
    const void* mask = d_in[3];
    const void* Wq = d_in[4];  const void* bq = d_in[5];
    const void* Wk = d_in[6];  const void* bk = d_in[7];
    const void* Wv = d_in[8];  const void* bv = d_in[9];
    const void* Wo = d_in[10]; const void* bo = d_in[11];
    float* out = (float*)d_out;

    char* ws = (char*)d_ws;
    float*  biasf = (float*)ws;                    // 1280 fp32
    ushort* Wt  = (ushort*)(ws + 8192);            // 393,216 ushorts
    ushort* Wot = Wt  + 393216;                    // 131,072
    ushort* qh  = Wot + 131072;                    // 1,048,576 each (2 MB)
    ushort* kh  = qh  + 1048576;
    ushort* vT  = kh  + 1048576;
    float*  pO  = (float*)(vT + 1048576);          // [2048<<chsh][512] fp32
    // chsh=2 needs pO 16.8MB + pl 0.5MB -> total 24,649,728 B (verified avail in R3)
    int chsh = (ws_size >= 24649728u) ? 2 : 1;
    float*  pl  = pO + ((size_t)2048 << chsh) * 512;

    transpose_w<<<513, 256, 0, stream>>>(Wq, Wk, Wv, Wo, bq, bk, bv, bo,
                                         (const ushort*)Q, Wt, Wot, biasf);
    qkv_gemm<<<dim3(256, 3), 256, 0, stream>>>(Q, K, V, Wt, biasf, qh, kh, vT);
    attn<<<128 << chsh, 512, 0, stream>>>(qh, kh, vT, mask, pO, pl, chsh);
    out_proj<<<512, 256, 0, stream>>>(pO, pl, Wot, biasf, out, chsh);
}

// Round 11
// 168.887 us; speedup vs baseline: 1.0856x; 1.0271x over previous
//
#include <hip/hip_runtime.h>

typedef __attribute__((ext_vector_type(8))) short bf16x8;
typedef __attribute__((ext_vector_type(4))) float f32x4;
typedef __attribute__((ext_vector_type(16))) float f32x16;

#define B_  2
#define S_  2048
#define DM  512
#define KD  256
#define HD  32
#define NH  8

__device__ __forceinline__ float bf2f(ushort u) {
    return __uint_as_float(((uint)u) << 16);
}
__device__ __forceinline__ ushort f2bf(float f) {
    uint x = __float_as_uint(f);
    return (ushort)((x + 0x7fffu + ((x >> 16) & 1u)) >> 16);  // RNE
}
// gfx950 packed f32->bf16 (RNE), 1 instr per 2 elements
__device__ __forceinline__ uint cvt_pk_bf16(float lo, float hi) {
    uint r;
    asm("v_cvt_pk_bf16_f32 %0, %1, %2" : "=v"(r) : "v"(lo), "v"(hi));
    return r;
}
#define MFMA __builtin_amdgcn_mfma_f32_16x16x32_bf16
#define MFMA32 __builtin_amdgcn_mfma_f32_32x32x16_bf16

__device__ __forceinline__ int detect_isbf(const ushort* __restrict__ q)
{
    int lane = threadIdx.x & 63;
    int e = (q[lane] >> 7) & 0xFF;
    unsigned long long m = __ballot(e >= 100 && e <= 133);
    return __popcll(m) >= 58;
}

// ---- W transposes + biases; output in PACKED fragment layout [n/16][k/8][16][8]
__global__ __launch_bounds__(256) void transpose_w(
    const void* __restrict__ Wq, const void* __restrict__ Wk, const void* __restrict__ Wv,
    const void* __restrict__ Wo,
    const void* __restrict__ bq, const void* __restrict__ bk,
    const void* __restrict__ bv, const void* __restrict__ bo,
    const ushort* __restrict__ qsrc,
    ushort* __restrict__ Wt, ushort* __restrict__ Wot, float* __restrict__ biasf)
{
    int isbf = detect_isbf(qsrc);
    int bid = blockIdx.x;
    if (bid >= 512) {
        for (int i = threadIdx.x; i < 1280; i += 256) {
            const void* bp; int off;
            if (i < 256)      { bp = bq; off = i; }
            else if (i < 512) { bp = bk; off = i - 256; }
            else if (i < 768) { bp = bv; off = i - 512; }
            else              { bp = bo; off = i - 768; }
            biasf[i] = isbf ? bf2f(((const ushort*)bp)[off]) : ((const float*)bp)[off];
        }
        return;
    }
    const void* W; int R, C; ushort* T;
    int m = bid >> 7, tix = bid & 127;
    if (m < 3) { W = (m == 0) ? Wq : (m == 1) ? Wk : Wv; R = 512; C = 256; T = Wt + m * 131072; }
    else       { W = Wo; R = 256; C = 512; T = Wot; }
    int tilesPerRow = C >> 5;
    int r0 = (tix / tilesPerRow) * 32, c0 = (tix % tilesPerRow) * 32;
    __shared__ float lds[32][33];
    int t = threadIdx.x;
    int rr = t >> 3, cc = (t & 7) * 4;
    if (isbf) {
        const ushort* Ws = (const ushort*)W;
        #pragma unroll
        for (int j = 0; j < 4; ++j) lds[rr][cc + j] = bf2f(Ws[(size_t)(r0 + rr) * C + c0 + cc + j]);
    } else {
        float4 v = *(const float4*)((const float*)W + (size_t)(r0 + rr) * C + c0 + cc);
        lds[rr][cc + 0] = v.x; lds[rr][cc + 1] = v.y; lds[rr][cc + 2] = v.z; lds[rr][cc + 3] = v.w;
    }
    __syncthreads();
    ushort4 o;
    o.x = f2bf(lds[cc + 0][rr]); o.y = f2bf(lds[cc + 1][rr]);
    o.z = f2bf(lds[cc + 2][rr]); o.w = f2bf(lds[cc + 3][rr]);
    int n = c0 + rr, k = r0 + cc;
    *(ushort4*)(T + ((((size_t)(n >> 4) * (R >> 3) + (k >> 3)) * 16 + (n & 15)) << 3) + (k & 7)) = o;
}

// ---- QKV GEMM (R9 version, unchanged): 16-row m-tiles, packed-B, cvt_pk;
// V written in MFMA32 B-frag packed layout [bh][s/16][d+32*((s>>3)&1)][s&7].
__global__ __launch_bounds__(256) void qkv_gemm(
    const void* __restrict__ Q, const void* __restrict__ K, const void* __restrict__ V,
    const ushort* __restrict__ Wt, const float* __restrict__ biasf,
    ushort* __restrict__ qh, ushort* __restrict__ kh, ushort* __restrict__ vT)
{
    int isbf = detect_isbf((const ushort*)Q);
    int y = blockIdx.y;
    const void* X = (y == 0) ? Q : (y == 1) ? K : V;
    int wave = threadIdx.x >> 6, lane = threadIdx.x & 63;
    int l16 = lane & 15, quad = lane >> 4;
    int m0 = blockIdx.x * 16;           // grid.x = 256
    int n0 = wave * 64;
    const ushort* W = Wt + (size_t)y * (256 * 512);

    auto loadA = [&](int ks, bf16x8* a) {
        if (isbf) {
            *a = *(const bf16x8*)((const ushort*)X + (size_t)(m0 + l16) * 512 + ks + quad * 8);
        } else {
            const float* p = (const float*)X + (size_t)(m0 + l16) * 512 + ks + quad * 8;
            float4 f0 = *(const float4*)p, f1 = *(const float4*)(p + 4);
            union { uint u[4]; bf16x8 v; } cv;
            cv.u[0] = cvt_pk_bf16(f0.x, f0.y);
            cv.u[1] = cvt_pk_bf16(f0.z, f0.w);
            cv.u[2] = cvt_pk_bf16(f1.x, f1.y);
            cv.u[3] = cvt_pk_bf16(f1.z, f1.w);
            *a = cv.v;
        }
    };
    auto loadB = [&](int ks, bf16x8* b) {
        #pragma unroll
        for (int j = 0; j < 4; ++j)
            b[j] = *(const bf16x8*)(W + (((size_t)((n0 >> 4) + j) * 64 + (ks >> 3) + quad) * 16 + l16) * 8);
    };

    f32x4 acc[4] = {};
    bf16x8 aC, bC[4], aN, bN[4];
    loadA(0, &aC); loadB(0, bC);
    for (int ks = 0; ks < 512; ks += 32) {
        if (ks + 32 < 512) { loadA(ks + 32, &aN); loadB(ks + 32, bN); }
        #pragma unroll
        for (int j = 0; j < 4; ++j)
            acc[j] = MFMA(aC, bC[j], acc[j], 0, 0, 0);
        aC = aN;
        #pragma unroll
        for (int j = 0; j < 4; ++j) bC[j] = bN[j];
    }
    if (y < 2) {
        ushort* out = (y == 0) ? qh : kh;
        #pragma unroll
        for (int j = 0; j < 4; ++j) {
            int n = n0 + 16 * j + l16;
            float bs = biasf[y * 256 + n];
            int h = n >> 5, d = n & 31;
            #pragma unroll
            for (int r = 0; r < 4; ++r) {
                int rg = m0 + quad * 4 + r;
                int bb = rg >> 11, ss = rg & 2047;
                out[((((size_t)bb * NH + h) * S_ + ss) << 5) + d] = f2bf(acc[j][r] + bs);
            }
        }
    } else {
        int rg0 = m0 + quad * 4;
        int bb = rg0 >> 11;
        int tt = (rg0 & 2047) >> 4;
        int sb = quad >> 1;
        int jb = (quad & 1) * 4;
        #pragma unroll
        for (int j = 0; j < 4; ++j) {
            int n = n0 + 16 * j + l16;
            float bs = biasf[2 * 256 + n];
            int h = n >> 5, d = n & 31;
            ushort4 o;
            o.x = f2bf(acc[j][0] + bs); o.y = f2bf(acc[j][1] + bs);
            o.z = f2bf(acc[j][2] + bs); o.w = f2bf(acc[j][3] + bs);
            *(ushort4*)(vT + ((((size_t)(bb * NH + h) * 128 + tt) * 64 + d + 32 * sb) << 3) + jb) = o;
        }
    }
}

// ---- attention (R10 head-grouped version, unchanged): 512 threads = 8 heads,
// mask staged once per block (L3 rebroadcast eliminated), in-register softmax.
__global__ __launch_bounds__(512) void attn(
    const ushort* __restrict__ qh, const ushort* __restrict__ kh,
    const ushort* __restrict__ vT, const void* __restrict__ maskp,
    float* __restrict__ pO, float* __restrict__ pl, int chsh)
{
    __shared__ float ldsM[2][32][33];   // 8.4 KB
    int isbf;
    {
        int lane = threadIdx.x & 63;
        ushort u = ((const ushort*)maskp)[lane];
        int e = (u >> 7) & 0xFF;
        unsigned long long m = __ballot(e >= 100 && e <= 133);
        isbf = __popcll(m) >= 58;
    }
    int tid = threadIdx.x;
    int wave = tid >> 6, lane = tid & 63;
    int l31 = lane & 31, hi = lane >> 5;
    int CH = 1 << chsh;
    int bid = blockIdx.x;                    // grid = 128 << chsh
    int chunk = bid & (CH - 1);
    int qt32 = (bid >> chsh) & 63;
    int b = bid >> (chsh + 6);
    int h = wave;                            // one head per wave
    int bh = b * NH + h;
    int q0 = qt32 * 32;
    int klen = 2048 >> chsh;
    int kbase = chunk * klen;
    int NT = klen >> 5;                      // 32-k substeps

    const ushort* qb = qh + (size_t)bh * S_ * HD;
    const ushort* kb = kh + (size_t)bh * S_ * HD;
    const ushort* vbp = vT + (size_t)bh * 65536;     // packed [s/16][lane][8]
    const ushort* mbb = (const ushort*)maskp + (size_t)b * S_ * S_;
    const float*  mbf = (const float*)maskp  + (size_t)b * S_ * S_;

    bf16x8 bq0 = *(const bf16x8*)(qb + (size_t)(q0 + l31) * HD + hi * 8);
    bf16x8 bq1 = *(const bf16x8*)(qb + (size_t)(q0 + l31) * HD + 16 + hi * 8);

    f32x16 O = {0,0,0,0,0,0,0,0,0,0,0,0,0,0,0,0};
    const f32x16 Z = {0,0,0,0,0,0,0,0,0,0,0,0,0,0,0,0};
    float lsum = 0.0f;

    // mask staging: 512 threads, one float2 each: row=tid>>4, col=(tid&15)*2
    int srow = tid >> 4, scol = (tid & 15) * 2;
    float2 g;

    auto loadMg = [&](int k0) {
        if (isbf) {
            ushort2 u = *(const ushort2*)(mbb + (size_t)(q0 + srow) * S_ + k0 + scol);
            g.x = bf2f(u.x); g.y = bf2f(u.y);
        } else {
            g = *(const float2*)(mbf + (size_t)(q0 + srow) * S_ + k0 + scol);
        }
    };
    auto writeM = [&](int buf) {
        ldsM[buf][srow][scol]     = g.x;
        ldsM[buf][srow][scol + 1] = g.y;
    };
    auto loadK = [&](int k0, bf16x8* K2) {
        K2[0] = *(const bf16x8*)(kb + (size_t)(k0 + l31) * HD + hi * 8);
        K2[1] = *(const bf16x8*)(kb + (size_t)(k0 + l31) * HD + 16 + hi * 8);
    };
    auto loadV = [&](int k0, bf16x8* V2) {
        int t0 = k0 >> 4;
        V2[0] = *(const bf16x8*)(vbp + (((size_t)t0 * 64 + lane) << 3));
        V2[1] = *(const bf16x8*)(vbp + (((size_t)(t0 + 1) * 64 + lane) << 3));
    };

    auto sub = [&](int buf, bf16x8* Kc, bf16x8* Vc, bf16x8* Kn, bf16x8* Vn, int t) {
        float Mreg[16];
        #pragma unroll
        for (int r = 0; r < 16; ++r)
            Mreg[r] = ldsM[buf][l31][(r & 3) + ((r >> 2) << 3) + (hi << 2)];
        int ktn = kbase + ((t + 1 < NT) ? (t + 1) : (NT - 1)) * 32;
        loadK(ktn, Kn); loadV(ktn, Vn);
        f32x16 S = MFMA32(Kc[0], bq0, Z, 0, 0, 0);
        S = MFMA32(Kc[1], bq1, S, 0, 0, 0);
        writeM(buf ^ 1);
        loadMg(kbase + ((t + 2 < NT) ? (t + 2) : (NT - 1)) * 32);
        float p[16];
        #pragma unroll
        for (int r = 0; r < 16; ++r) {
            p[r] = __expf(fmaf(S[r], 0.0625f, Mreg[r]));
            lsum += p[r];
        }
        union { uint u[4]; bf16x8 v; } pa0, pa1;
        {
            uint u0 = cvt_pk_bf16(p[0], p[1]),  w0 = cvt_pk_bf16(p[4], p[5]);
            uint u1 = cvt_pk_bf16(p[2], p[3]),  w1 = cvt_pk_bf16(p[6], p[7]);
            asm volatile("v_permlane32_swap_b32 %0, %1" : "+v"(u0), "+v"(w0));
            asm volatile("v_permlane32_swap_b32 %0, %1" : "+v"(u1), "+v"(w1));
            pa0.u[0] = u0; pa0.u[1] = u1; pa0.u[2] = w0; pa0.u[3] = w1;
            uint u2 = cvt_pk_bf16(p[8], p[9]),   w2 = cvt_pk_bf16(p[12], p[13]);
            uint u3 = cvt_pk_bf16(p[10], p[11]), w3 = cvt_pk_bf16(p[14], p[15]);
            asm volatile("v_permlane32_swap_b32 %0, %1" : "+v"(u2), "+v"(w2));
            asm volatile("v_permlane32_swap_b32 %0, %1" : "+v"(u3), "+v"(w3));
            pa1.u[0] = u2; pa1.u[1] = u3; pa1.u[2] = w2; pa1.u[3] = w3;
        }
        O = MFMA32(pa0.v, Vc[0], O, 0, 0, 0);
        O = MFMA32(pa1.v, Vc[1], O, 0, 0, 0);
        __syncthreads();   // tile t fully read; tile t+1 writes visible
    };

    bf16x8 KA[2], VA[2], KB[2], VB[2];
    loadK(kbase, KA); loadV(kbase, VA);
    loadMg(kbase); writeM(0);
    loadMg(kbase + ((1 < NT) ? 32 : 0));
    __syncthreads();
    for (int t = 0; t < NT; t += 2) {
        sub(0, KA, VA, KB, VB, t);
        sub(1, KB, VB, KA, VA, t + 1);
    }

    float tot = lsum + __shfl_xor(lsum, 32, 64);
    int wid16_0 = (((bh << 7) + qt32 * 2 + 0) << chsh) + chunk;
    int wid16_1 = (((bh << 7) + qt32 * 2 + 1) << chsh) + chunk;
    if (lane < 32) {
        int q = l31;
        int w16 = (q < 16) ? wid16_0 : wid16_1;
        pl[w16 * 16 + (q & 15)] = tot;
    }
    #pragma unroll
    for (int r = 0; r < 16; ++r) {
        int q = (r & 3) + ((r >> 2) << 3) + (hi << 2);
        int w16 = (q < 16) ? wid16_0 : wid16_1;
        pO[(size_t)w16 * 512 + (q & 15) * 32 + l31] = O[r];
    }
}

// ---- out projection. R14: depth-1 software pipeline — pO/pl/B loads for
// step ks+32 issued BEFORE the A-build+MFMAs of step ks (same pattern as
// qkv_gemm's proven k-pipeline; previously every step serially waited on 8
// strided pO gathers before any MFMA). Templated on CH so the in-flight
// float4 u[8] is compile-time indexed (no scratch).
template <int CH>
__global__ __launch_bounds__(256) void out_proj(
    const float* __restrict__ pO, const float* __restrict__ pl,
    const ushort* __restrict__ Wot, const float* __restrict__ biasf,
    float* __restrict__ out)
{
    constexpr int chsh = (CH == 4) ? 2 : 1;
    int wave = threadIdx.x >> 6, lane = threadIdx.x & 63;
    int l16 = lane & 15, quad = lane >> 4;
    int m0 = (blockIdx.x >> 1) * 16;                  // grid = 512
    int n0 = (blockIdx.x & 1) * 256 + wave * 64;
    int row = m0 + l16;
    int bb = row >> 11, s = row & 2047;
    int qt = s >> 4, r16 = s & 15;

    auto loadP = [&](int ks, float4* u, float& lac) {
        int h = ks >> 5;
        int wid0 = (((bb * NH + h) << 7) + qt) << chsh;
        lac = 0.0f;
        #pragma unroll
        for (int cc = 0; cc < CH; ++cc) {
            const float* p = pO + ((size_t)(wid0 + cc) << 9) + r16 * 32 + quad * 8;
            u[cc * 2]     = *(const float4*)p;
            u[cc * 2 + 1] = *(const float4*)(p + 4);
            lac += pl[(wid0 + cc) * 16 + r16];
        }
    };
    auto loadB = [&](int ks, bf16x8* b) {
        #pragma unroll
        for (int j = 0; j < 4; ++j)
            b[j] = *(const bf16x8*)(Wot + (((size_t)((n0 >> 4) + j) * 32 + (ks >> 3) + quad) * 16 + l16) * 8);
    };

    f32x4 acc[4] = {};
    float4 uC[2 * CH], uN[2 * CH];
    float lacC, lacN;
    bf16x8 bC[4], bN[4];
    loadP(0, uC, lacC); loadB(0, bC);
    for (int ks = 0; ks < 256; ks += 32) {
        if (ks + 32 < 256) { loadP(ks + 32, uN, lacN); loadB(ks + 32, bN); }
        bf16x8 a;
        {
            float s8[8] = {0, 0, 0, 0, 0, 0, 0, 0};
            #pragma unroll
            for (int cc = 0; cc < CH; ++cc) {
                s8[0] += uC[cc * 2].x;     s8[1] += uC[cc * 2].y;
                s8[2] += uC[cc * 2].z;     s8[3] += uC[cc * 2].w;
                s8[4] += uC[cc * 2 + 1].x; s8[5] += uC[cc * 2 + 1].y;
                s8[6] += uC[cc * 2 + 1].z; s8[7] += uC[cc * 2 + 1].w;
            }
            float il = 1.0f / lacC;
            union { uint u[4]; bf16x8 v; } cv;
            cv.u[0] = cvt_pk_bf16(s8[0] * il, s8[1] * il);
            cv.u[1] = cvt_pk_bf16(s8[2] * il, s8[3] * il);
            cv.u[2] = cvt_pk_bf16(s8[4] * il, s8[5] * il);
            cv.u[3] = cvt_pk_bf16(s8[6] * il, s8[7] * il);
            a = cv.v;
        }
        #pragma unroll
        for (int j = 0; j < 4; ++j)
            acc[j] = MFMA(a, bC[j], acc[j], 0, 0, 0);
        #pragma unroll
        for (int i = 0; i < 2 * CH; ++i) uC[i] = uN[i];
        lacC = lacN;
        #pragma unroll
        for (int j = 0; j < 4; ++j) bC[j] = bN[j];
    }
    #pragma unroll
    for (int j = 0; j < 4; ++j) {
        int n = n0 + 16 * j + l16;
        float bs = biasf[768 + n];
        #pragma unroll
        for (int r = 0; r < 4; ++r) {
            int rg = m0 + 16 * 0 + quad * 4 + r;
            out[(size_t)(m0 + quad * 4 + r) * DM + n] = acc[j][r] + bs;
            (void)rg;
        }
    }
}

extern "C" void kernel_launch(void* const* d_in, const int* in_sizes, int n_in,
                              void* d_out, int out_size, void* d_ws, size_t ws_size,
                              hipStream_t stream)
{
    const void* V    = d_in[0];
    const void* Q    = d_in[1];
    const void* K    = d_in[2];
    const void* mask = d_in[3];
    const void* Wq = d_in[4];  const void* bq = d_in[5];
    const void* Wk = d_in[6];  const void* bk = d_in[7];
    const void* Wv = d_in[8];  const void* bv = d_in[9];
    const void* Wo = d_in[10]; const void* bo = d_in[11];
    float* out = (float*)d_out;

    char* ws = (char*)d_ws;
    float*  biasf = (float*)ws;                    // 1280 fp32
    ushort* Wt  = (ushort*)(ws + 8192);            // 393,216 ushorts
    ushort* Wot = Wt  + 393216;                    // 131,072
    ushort* qh  = Wot + 131072;                    // 1,048,576 each (2 MB)
    ushort* kh  = qh  + 1048576;
    ushort* vT  = kh  + 1048576;
    float*  pO  = (float*)(vT + 1048576);          // [2048<<chsh][512] fp32
    int chsh = (ws_size >= 24649728u) ? 2 : 1;
    float*  pl  = pO + ((size_t)2048 << chsh) * 512;

    transpose_w<<<513, 256, 0, stream>>>(Wq, Wk, Wv, Wo, bq, bk, bv, bo,
                                         (const ushort*)Q, Wt, Wot, biasf);
    qkv_gemm<<<dim3(256, 3), 256, 0, stream>>>(Q, K, V, Wt, biasf, qh, kh, vT);
    attn<<<128 << chsh, 512, 0, stream>>>(qh, kh, vT, mask, pO, pl, chsh);
    if (chsh == 2)
        out_proj<4><<<512, 256, 0, stream>>>(pO, pl, Wot, biasf, out);
    else
        out_proj<2><<<512, 256, 0, stream>>>(pO, pl, Wot, biasf, out);
}